// Round 2
// baseline (180.481 us; speedup 1.0000x reference)
//
#include <hip/hip_runtime.h>
#include <math.h>

#define B_ 2
#define N_ 400
#define F_ 246
#define C_ 32
#define LBL_ 1440
#define NODE_IN_ 310   // F + 2C
#define RT_ 8          // row tile for k_out

// ---------------------------------------------------------------------------
// K1: P[b,n,c] = x[b,n,:] @ W_stack[0:F, c]   (x_i term)
//     Q[b,n,c] = x[b,n,:] @ W_stack[F:2F, c]  (x_j term)
// grid = B*N blocks, 64 threads (lanes 0-31 -> P, 32-63 -> Q)
// ---------------------------------------------------------------------------
__global__ void k_pq(const float* __restrict__ x, const float* __restrict__ Ws,
                     float* __restrict__ P, float* __restrict__ Q) {
    int row = blockIdx.x;              // b*N + n
    int tid = threadIdx.x;             // 0..63
    __shared__ float xs[F_];
    const float* xrow = x + row * F_;
    for (int k = tid; k < F_; k += 64) xs[k] = xrow[k];
    __syncthreads();
    int c   = tid & 31;
    int isQ = tid >> 5;
    const float* wbase = Ws + (isQ ? F_ * C_ : 0) + c;
    float acc = 0.f;
    #pragma unroll 2
    for (int k = 0; k < F_; ++k) acc += xs[k] * wbase[k * C_];
    (isQ ? Q : P)[row * C_ + c] = acc;
}

// ---------------------------------------------------------------------------
// K2: aggregation. grid = 2*B*N blocks.
//   mode 0 (blk <  B*N): fixed i = n, loop j  -> AGG_I[b,i,c] (sum_j s*att_i)
//   mode 1 (blk >= B*N): fixed j = n, loop i  -> AGG_J[b,j,c] (sum_i s*att_j)
// 256 threads = 8 groups x 32 lanes (lane = channel c). a-mask is uniform
// within a group so the ~90% a==0 pairs are skipped with no lane divergence.
// ---------------------------------------------------------------------------
__global__ void k_agg(const float* __restrict__ a, const float* __restrict__ e,
                      const float* __restrict__ Ws, const float* __restrict__ bs,
                      const float* __restrict__ alpha,
                      const float* __restrict__ Wai, const float* __restrict__ bai,
                      const float* __restrict__ Waj, const float* __restrict__ baj,
                      const float* __restrict__ P, const float* __restrict__ Q,
                      float* __restrict__ AGGI, float* __restrict__ AGGJ) {
    int blk  = blockIdx.x;
    int mode = (blk >= B_ * N_) ? 1 : 0;
    int row  = mode ? blk - B_ * N_ : blk;   // b*N + n
    int b = row / N_, n = row % N_;
    int tid = threadIdx.x;
    int c = tid & 31, g = tid >> 5;

    float w3  = Ws[(2 * F_) * C_ + c];       // weight row for e_ij
    float w4  = Ws[(2 * F_ + 1) * C_ + c];   // weight row for e_ji
    float bsc = bs[c];
    float alc = alpha[c];
    float wat = mode ? Waj[c] : Wai[c];
    float bat = mode ? baj[0] : bai[0];

    // mode 0: own = P[b,i,:], other(m) = Q[b,m,:] (m = j)
    // mode 1: own = Q[b,j,:], other(m) = P[b,m,:] (m = i)
    const float* own = (mode ? Q : P) + row * C_;
    const float* oth = (mode ? P : Q) + b * N_ * C_;
    float ownc = own[c];

    const float* abase = a + (size_t)b * N_ * N_;
    const float* ebase = e + (size_t)b * N_ * N_;

    float acc = 0.f;
    for (int m = g; m < N_; m += 8) {
        int i = mode ? m : n;
        int j = mode ? n : m;
        float aij = abase[i * N_ + j];
        if (aij != 0.f) {                         // uniform across the 32-lane group
            float eij = ebase[i * N_ + j];
            float eji = ebase[j * N_ + i];
            float raw = ownc + oth[m * C_ + c] + eij * w3 + eji * w4 + bsc;
            float s = (raw >= 0.f ? raw : alc * raw) * aij;   // PReLU then mask
            float t = s * wat;                    // butterfly dot over 32 channels
            t += __shfl_xor(t, 1, 32);
            t += __shfl_xor(t, 2, 32);
            t += __shfl_xor(t, 4, 32);
            t += __shfl_xor(t, 8, 32);
            t += __shfl_xor(t, 16, 32);
            float att = 1.f / (1.f + __expf(-(t + bat)));
            acc += s * att;
        }
    }
    __shared__ float part[8][C_];
    part[g][c] = acc;
    __syncthreads();
    if (tid < C_) {
        float tot = 0.f;
        #pragma unroll
        for (int gg = 0; gg < 8; ++gg) tot += part[gg][c];
        (mode ? AGGJ : AGGI)[row * C_ + c] = tot;
    }
}

// ---------------------------------------------------------------------------
// K3: x_new[b,n,f] = concat(x, agg_i, agg_j) @ W_node + b_node  (fp32 in ws)
// grid = B*N blocks, 256 threads (thread f computes one output, f < 246)
// ---------------------------------------------------------------------------
__global__ void k_node(const float* __restrict__ x, const float* __restrict__ AGGI,
                       const float* __restrict__ AGGJ, const float* __restrict__ Wn,
                       const float* __restrict__ bn, float* __restrict__ XNEW) {
    int row = blockIdx.x;
    int tid = threadIdx.x;
    __shared__ float cc[NODE_IN_];
    const float* xrow = x + row * F_;
    for (int k = tid; k < F_; k += 256) cc[k] = xrow[k];
    if (tid < C_) {
        cc[F_ + tid]      = AGGI[row * C_ + tid];
        cc[F_ + C_ + tid] = AGGJ[row * C_ + tid];
    }
    __syncthreads();
    if (tid < F_) {
        float acc = bn[tid];
        for (int k = 0; k < NODE_IN_; ++k)
            acc += cc[k] * Wn[k * F_ + tid];
        XNEW[row * F_ + tid] = acc;
    }
}

// ---------------------------------------------------------------------------
// K4: out[b,n,l] = x_new[b,n,:] @ W_out[:,l] + b_out[l]
// grid = dim3(ceil(1440/256)=6, (B*N)/8=100); 8-row tile reuses each W_out
// column-load 8x. Per-block W traffic 252 KB -> 147 MB total from L2.
// ---------------------------------------------------------------------------
__global__ void k_out(const float* __restrict__ XNEW, const float* __restrict__ Wo,
                      const float* __restrict__ bo, float* __restrict__ out) {
    int ct  = blockIdx.x;            // column tile
    int rt  = blockIdx.y;            // row tile
    int tid = threadIdx.x;
    int l   = ct * 256 + tid;
    int r0  = rt * RT_;
    __shared__ float xs[RT_ * F_];   // 8 rows x 246 = 7.9 KB
    for (int idx = tid; idx < RT_ * F_; idx += 256)
        xs[idx] = XNEW[r0 * F_ + idx];      // rows are contiguous
    __syncthreads();
    if (l < LBL_) {
        float acc[RT_];
        #pragma unroll
        for (int r = 0; r < RT_; ++r) acc[r] = 0.f;
        const float* wcol = Wo + l;
        for (int f = 0; f < F_; ++f) {
            float w = wcol[f * LBL_];        // coalesced across threads (l contiguous)
            #pragma unroll
            for (int r = 0; r < RT_; ++r) acc[r] += xs[r * F_ + f] * w;
        }
        float bv = bo[l];
        #pragma unroll
        for (int r = 0; r < RT_; ++r)
            out[(size_t)(r0 + r) * LBL_ + l] = acc[r] + bv;
    }
}

// ---------------------------------------------------------------------------
extern "C" void kernel_launch(void* const* d_in, const int* in_sizes, int n_in,
                              void* d_out, int out_size, void* d_ws, size_t ws_size,
                              hipStream_t stream) {
    const float* x   = (const float*)d_in[0];
    const float* a   = (const float*)d_in[1];
    const float* e   = (const float*)d_in[2];
    const float* Ws  = (const float*)d_in[3];
    const float* bs  = (const float*)d_in[4];
    const float* al  = (const float*)d_in[5];
    const float* Wai = (const float*)d_in[6];
    const float* bai = (const float*)d_in[7];
    const float* Waj = (const float*)d_in[8];
    const float* baj = (const float*)d_in[9];
    const float* Wn  = (const float*)d_in[10];
    const float* bn  = (const float*)d_in[11];
    const float* Wo  = (const float*)d_in[12];
    const float* bo  = (const float*)d_in[13];

    float* ws   = (float*)d_ws;
    float* P    = ws;                       // B*N*C = 25600 floats
    float* Q    = P    + B_ * N_ * C_;
    float* AGGI = Q    + B_ * N_ * C_;
    float* AGGJ = AGGI + B_ * N_ * C_;
    float* XNEW = AGGJ + B_ * N_ * C_;      // B*N*F = 196800 floats

    k_pq  <<<B_ * N_,      64, 0, stream>>>(x, Ws, P, Q);
    k_agg <<<2 * B_ * N_, 256, 0, stream>>>(a, e, Ws, bs, al, Wai, bai, Waj, baj,
                                            P, Q, AGGI, AGGJ);
    k_node<<<B_ * N_,     256, 0, stream>>>(x, AGGI, AGGJ, Wn, bn, XNEW);
    k_out <<<dim3((LBL_ + 255) / 256, (B_ * N_) / RT_), 256, 0, stream>>>(
        XNEW, Wo, bo, (float*)d_out);
}